// Round 4
// baseline (101.369 us; speedup 1.0000x reference)
//
#include <hip/hip_runtime.h>
#include <hip/hip_bf16.h>

#define NN 8192
#define DD 256
#define EE (NN - 1)

typedef __attribute__((ext_vector_type(8))) short bf16x8;
typedef __attribute__((ext_vector_type(4))) float f32x4;

__device__ inline unsigned short f2bf(float f) {
  return __builtin_bit_cast(unsigned short, __float2bfloat16(f));
}

// ---------------------------------------------------------------------------
// prep: single block, 1024 threads.
//   inv[i] = -1; inv[gov[e]] = e
//   u = W^T a[:D], v = W^T a[D:]   (exact f32; carries the sign of s)
// ---------------------------------------------------------------------------
__global__ __launch_bounds__(1024) void prep(
    const float* __restrict__ W, const float* __restrict__ a,
    const int* __restrict__ gov,
    float* __restrict__ u, float* __restrict__ v, int* __restrict__ inv) {
  const int t = threadIdx.x;
  const int k = t & 255, part = t >> 8;

  for (int i = t; i < NN; i += 1024) inv[i] = -1;
  __syncthreads();
  for (int e = t; e < EE; e += 1024) inv[gov[e]] = e;

  float up = 0.f, vp = 0.f;
  const int j0 = part * 64;
  for (int j = j0; j < j0 + 64; ++j) {
    float w = W[(size_t)j * DD + k];   // coalesced across k
    up = fmaf(a[j], w, up);
    vp = fmaf(a[DD + j], w, vp);
  }
  __shared__ float redu[4][256], redv[4][256];
  redu[part][k] = up; redv[part][k] = vp;
  __syncthreads();
  if (t < 256) {
    u[t] = redu[0][t] + redu[1][t] + redu[2][t] + redu[3][t];
    v[t] = redv[0][t] + redv[1][t] + redv[2][t] + redv[3][t];
  }
}

// ---------------------------------------------------------------------------
// pq: p[i] = x[i]·u, q[i] = x[i]·v  (f32 exact). One wave per row.
// ---------------------------------------------------------------------------
__global__ __launch_bounds__(256) void pq_kernel(
    const float* __restrict__ x, const float* __restrict__ u,
    const float* __restrict__ v, float* __restrict__ p, float* __restrict__ q) {
  const int wid = threadIdx.x >> 6, lane = threadIdx.x & 63;
  const int row = blockIdx.x * 4 + wid;
  const float4 xv = *(const float4*)&x[(size_t)row * DD + lane * 4];
  const float4 uv = *(const float4*)&u[lane * 4];
  const float4 vv = *(const float4*)&v[lane * 4];
  float ps = xv.x * uv.x + xv.y * uv.y + xv.z * uv.z + xv.w * uv.w;
  float qs = xv.x * vv.x + xv.y * vv.y + xv.z * vv.z + xv.w * vv.w;
#pragma unroll
  for (int off = 32; off; off >>= 1) {
    ps += __shfl_xor(ps, off);
    qs += __shfl_xor(qs, off);
  }
  if (lane == 0) { p[row] = ps; q[row] = qs; }
}

// ---------------------------------------------------------------------------
// gemm_mfma: Hx = bf16(X) @ bf16(W)^T in f32 accum via mfma_f32_16x16x32_bf16.
// 128x64 tile, 4 waves (each 64x32), BK=32, convert-on-stage, pad-40 LDS rows
// (80 B: 16B-aligned b128 frag reads, <=2-way bank aliasing).
// ---------------------------------------------------------------------------
#define BM 128
#define BN 64
#define BK 32
#define LDAB 40

__global__ __launch_bounds__(256) void gemm_mfma(
    const float* __restrict__ X, const float* __restrict__ W,
    float* __restrict__ Hx) {
  __shared__ unsigned short As[BM][LDAB];
  __shared__ unsigned short Bs[BN][LDAB];
  const int t = threadIdx.x;
  const int bm = blockIdx.x * BM, bn = blockIdx.y * BN;
  const int lane = t & 63;
  const int wid = t >> 6;
  const int wr = wid >> 1, wc = wid & 1;     // wave -> 64-row x 32-col subtile
  const int l15 = lane & 15, l4 = lane >> 4;

  f32x4 acc[4][2] = {};

  const int arow = t >> 1, ahalf = t & 1;    // A stage: 2 thr/row, 4 float4 each
  const int brow = t >> 2, bq = t & 3;       // B stage: 4 thr/row, 2 float4 each

  for (int k0 = 0; k0 < DD; k0 += BK) {
    {
      const float* src = &X[(size_t)(bm + arow) * DD + k0 + ahalf * 16];
#pragma unroll
      for (int i = 0; i < 4; ++i) {
        float4 f = *(const float4*)(src + i * 4);
        ushort4 pk;
        pk.x = f2bf(f.x); pk.y = f2bf(f.y); pk.z = f2bf(f.z); pk.w = f2bf(f.w);
        *(ushort4*)&As[arow][ahalf * 16 + i * 4] = pk;
      }
    }
    {
      const float* src = &W[(size_t)(bn + brow) * DD + k0 + bq * 8];
#pragma unroll
      for (int i = 0; i < 2; ++i) {
        float4 f = *(const float4*)(src + i * 4);
        ushort4 pk;
        pk.x = f2bf(f.x); pk.y = f2bf(f.y); pk.z = f2bf(f.z); pk.w = f2bf(f.w);
        *(ushort4*)&Bs[brow][bq * 8 + i * 4] = pk;
      }
    }
    __syncthreads();

    bf16x8 af[4], bfr[2];
#pragma unroll
    for (int mf = 0; mf < 4; ++mf)
      af[mf] = *(const bf16x8*)&As[wr * 64 + mf * 16 + l15][l4 * 8];
#pragma unroll
    for (int nf = 0; nf < 2; ++nf)
      bfr[nf] = *(const bf16x8*)&Bs[wc * 32 + nf * 16 + l15][l4 * 8];
#pragma unroll
    for (int mf = 0; mf < 4; ++mf)
#pragma unroll
      for (int nf = 0; nf < 2; ++nf)
        acc[mf][nf] = __builtin_amdgcn_mfma_f32_16x16x32_bf16(
            af[mf], bfr[nf], acc[mf][nf], 0, 0, 0);
    __syncthreads();
  }

  // C/D layout (m89): col = lane&15, row = (lane>>4)*4 + reg
#pragma unroll
  for (int mf = 0; mf < 4; ++mf)
#pragma unroll
    for (int nf = 0; nf < 2; ++nf)
#pragma unroll
      for (int r = 0; r < 4; ++r) {
        const int row = bm + wr * 64 + mf * 16 + l4 * 4 + r;
        const int col = bn + wc * 32 + nf * 16 + l15;
        Hx[(size_t)row * DD + col] = acc[mf][nf][r];
      }
}

// ---------------------------------------------------------------------------
// finalize: out[j] = leaky( (j>0 ? Hx[gov[j-1]] : 0)
//                           + (inv[j]>=0 ? coef(p[j]+q[d]) * Hx[d] : 0) )
// 64 lanes per row (float4 each), no reductions.
// ---------------------------------------------------------------------------
__global__ __launch_bounds__(256) void finalize(
    const float* __restrict__ Hx, const float* __restrict__ p,
    const float* __restrict__ q, const int* __restrict__ gov,
    const int* __restrict__ inv, float* __restrict__ out) {
  const int sub = threadIdx.x >> 6, c4 = threadIdx.x & 63;
  const int j = blockIdx.x * 4 + sub;

  float4 h = make_float4(0.f, 0.f, 0.f, 0.f);
  if (j > 0) {
    const int g = gov[j - 1];
    h = *(const float4*)&Hx[(size_t)g * DD + c4 * 4];
  }
  const int e2 = inv[j];
  if (e2 >= 0) {
    const int d = e2 + 1;
    const float4 hd = *(const float4*)&Hx[(size_t)d * DD + c4 * 4];
    const float s = p[j] + q[d];
    const float coef = (s > 0.f) ? 1.f : (1.f / 8192.f);
    h.x = fmaf(coef, hd.x, h.x);
    h.y = fmaf(coef, hd.y, h.y);
    h.z = fmaf(coef, hd.z, h.z);
    h.w = fmaf(coef, hd.w, h.w);
  }
  float4 o;
  o.x = (h.x >= 0.f) ? h.x : 0.2f * h.x;
  o.y = (h.y >= 0.f) ? h.y : 0.2f * h.y;
  o.z = (h.z >= 0.f) ? h.z : 0.2f * h.z;
  o.w = (h.w >= 0.f) ? h.w : 0.2f * h.w;
  *(float4*)&out[(size_t)j * DD + c4 * 4] = o;
}

extern "C" void kernel_launch(void* const* d_in, const int* in_sizes, int n_in,
                              void* d_out, int out_size, void* d_ws, size_t ws_size,
                              hipStream_t stream) {
  const float* x = (const float*)d_in[0];
  const float* W = (const float*)d_in[1];
  const float* a = (const float*)d_in[2];
  const int* gov = (const int*)d_in[4];

  float* Hx = (float*)d_ws;                  // 8 MB
  float* p  = Hx + (size_t)NN * DD;          // 32 KB
  float* q  = p + NN;                        // 32 KB
  float* u  = q + NN;                        // 1 KB
  float* v  = u + DD;                        // 1 KB
  int* inv  = (int*)(v + DD);                // 32 KB

  hipLaunchKernelGGL(prep, dim3(1), dim3(1024), 0, stream, W, a, gov, u, v, inv);
  hipLaunchKernelGGL(pq_kernel, dim3(NN / 4), dim3(256), 0, stream, x, u, v, p, q);
  hipLaunchKernelGGL(gemm_mfma, dim3(NN / BM, DD / BN), dim3(256), 0, stream,
                     x, W, Hx);
  hipLaunchKernelGGL(finalize, dim3(NN / 4), dim3(256), 0, stream,
                     Hx, p, q, gov, inv, (float*)d_out);
}

// Round 5
// 96.936 us; speedup vs baseline: 1.0457x; 1.0457x over previous
//
#include <hip/hip_runtime.h>
#include <hip/hip_bf16.h>

#define NN 8192
#define DD 256
#define EE (NN - 1)

typedef __attribute__((ext_vector_type(8))) short bf16x8;
typedef __attribute__((ext_vector_type(4))) float f32x4;

__device__ inline unsigned short f2bf(float f) {
  return __builtin_bit_cast(unsigned short, __float2bfloat16(f));
}

// ---------------------------------------------------------------------------
// prep: single block, 1024 threads.
//   inv[i] = -1; inv[gov[e]] = e   (ordered via __syncthreads within the block)
//   u = W^T a[:D], v = W^T a[D:]   (exact f32; carries the sign of s)
// ---------------------------------------------------------------------------
__global__ __launch_bounds__(1024) void prep(
    const float* __restrict__ W, const float* __restrict__ a,
    const int* __restrict__ gov,
    float* __restrict__ u, float* __restrict__ v, int* __restrict__ inv) {
  const int t = threadIdx.x;
  const int k = t & 255, part = t >> 8;

  for (int i = t; i < NN; i += 1024) inv[i] = -1;
  __syncthreads();
  for (int e = t; e < EE; e += 1024) inv[gov[e]] = e;

  float up = 0.f, vp = 0.f;
  const int j0 = part * 64;
#pragma unroll 4
  for (int j = j0; j < j0 + 64; ++j) {
    float w = W[(size_t)j * DD + k];   // coalesced across k
    up = fmaf(a[j], w, up);
    vp = fmaf(a[DD + j], w, vp);
  }
  __shared__ float redu[4][256], redv[4][256];
  redu[part][k] = up; redv[part][k] = vp;
  __syncthreads();
  if (t < 256) {
    u[t] = redu[0][t] + redu[1][t] + redu[2][t] + redu[3][t];
    v[t] = redv[0][t] + redv[1][t] + redv[2][t] + redv[3][t];
  }
}

// ---------------------------------------------------------------------------
// pq: p[i] = x[i]·u, q[i] = x[i]·v  (f32 exact, same reassociation that passed
// in round 4 -> same s signs). One wave per row.
// ---------------------------------------------------------------------------
__global__ __launch_bounds__(256) void pq_kernel(
    const float* __restrict__ x, const float* __restrict__ u,
    const float* __restrict__ v, float* __restrict__ p, float* __restrict__ q) {
  const int wid = threadIdx.x >> 6, lane = threadIdx.x & 63;
  const int row = blockIdx.x * 4 + wid;
  const float4 xv = *(const float4*)&x[(size_t)row * DD + lane * 4];
  const float4 uv = *(const float4*)&u[lane * 4];
  const float4 vv = *(const float4*)&v[lane * 4];
  float ps = xv.x * uv.x + xv.y * uv.y + xv.z * uv.z + xv.w * uv.w;
  float qs = xv.x * vv.x + xv.y * vv.y + xv.z * vv.z + xv.w * vv.w;
#pragma unroll
  for (int off = 32; off; off >>= 1) {
    ps += __shfl_xor(ps, off);
    qs += __shfl_xor(qs, off);
  }
  if (lane == 0) { p[row] = ps; q[row] = qs; }
}

// ---------------------------------------------------------------------------
// combine: y[j] = bf16( (j>0 ? x[gov[j-1]] : 0) + (inv[j]>=0 ? coef*x[d] : 0) )
//   coef = (p[j]+q[d] > 0) ? 1 : 1/8192,  d = inv[j]+1
// Gathered rows read as full 1 KB rows (coalesced within the 64-lane group).
// ---------------------------------------------------------------------------
__global__ __launch_bounds__(256) void combine(
    const float* __restrict__ x, const float* __restrict__ p,
    const float* __restrict__ q, const int* __restrict__ gov,
    const int* __restrict__ inv, unsigned short* __restrict__ y) {
  const int sub = threadIdx.x >> 6, lane = threadIdx.x & 63;
  const int j = blockIdx.x * 4 + sub;

  float4 h = make_float4(0.f, 0.f, 0.f, 0.f);
  if (j > 0) {
    const int g = gov[j - 1];
    h = *(const float4*)&x[(size_t)g * DD + lane * 4];
  }
  const int e2 = inv[j];
  if (e2 >= 0) {
    const int d = e2 + 1;
    const float4 xd = *(const float4*)&x[(size_t)d * DD + lane * 4];
    const float s = p[j] + q[d];
    const float coef = (s > 0.f) ? 1.f : (1.f / 8192.f);
    h.x = fmaf(coef, xd.x, h.x);
    h.y = fmaf(coef, xd.y, h.y);
    h.z = fmaf(coef, xd.z, h.z);
    h.w = fmaf(coef, xd.w, h.w);
  }
  ushort4 pk;
  pk.x = f2bf(h.x); pk.y = f2bf(h.y); pk.z = f2bf(h.z); pk.w = f2bf(h.w);
  *(ushort4*)&y[(size_t)j * DD + lane * 4] = pk;
}

// ---------------------------------------------------------------------------
// gemm: out = leaky_relu( y_bf16 @ bf16(W)^T ), f32 accum via mfma 16x16x32.
// 64x64 tile, 4 waves (2x2, each 32x32), BK=32, grid 128x4 = 512 blocks.
// LDS rows padded to 40 shorts (80 B): 16B-aligned b128 frags, <=2-way banks.
// ---------------------------------------------------------------------------
#define BM 64
#define BN 64
#define BK 32
#define LDAB 40

__global__ __launch_bounds__(256) void gemm_out(
    const unsigned short* __restrict__ Y, const float* __restrict__ W,
    float* __restrict__ out) {
  __shared__ unsigned short As[BM][LDAB];
  __shared__ unsigned short Bs[BN][LDAB];
  const int t = threadIdx.x;
  const int bm = blockIdx.x * BM, bn = blockIdx.y * BN;
  const int lane = t & 63, wid = t >> 6;
  const int wr = wid >> 1, wc = wid & 1;      // wave -> 32x32 subtile
  const int l15 = lane & 15, l4 = lane >> 4;
  const int srow = t >> 2, sseg = t & 3;      // stage: 4 thr/row, 16B(bf16)/32B(f32)

  f32x4 acc[2][2] = {};

  for (int k0 = 0; k0 < DD; k0 += BK) {
    {  // A: bf16 y, 64 rows x 32 shorts
      ushort4 w0 = *(const ushort4*)&Y[(size_t)(bm + srow) * DD + k0 + sseg * 8];
      ushort4 w1 = *(const ushort4*)&Y[(size_t)(bm + srow) * DD + k0 + sseg * 8 + 4];
      *(ushort4*)&As[srow][sseg * 8] = w0;
      *(ushort4*)&As[srow][sseg * 8 + 4] = w1;
    }
    {  // B: f32 W -> bf16, 64 rows x 32 floats
      const float* src = &W[(size_t)(bn + srow) * DD + k0 + sseg * 8];
      float4 f0 = *(const float4*)src;
      float4 f1 = *(const float4*)(src + 4);
      ushort4 p0, p1;
      p0.x = f2bf(f0.x); p0.y = f2bf(f0.y); p0.z = f2bf(f0.z); p0.w = f2bf(f0.w);
      p1.x = f2bf(f1.x); p1.y = f2bf(f1.y); p1.z = f2bf(f1.z); p1.w = f2bf(f1.w);
      *(ushort4*)&Bs[srow][sseg * 8] = p0;
      *(ushort4*)&Bs[srow][sseg * 8 + 4] = p1;
    }
    __syncthreads();

    bf16x8 af[2], bfr[2];
#pragma unroll
    for (int mf = 0; mf < 2; ++mf)
      af[mf] = *(const bf16x8*)&As[wr * 32 + mf * 16 + l15][l4 * 8];
#pragma unroll
    for (int nf = 0; nf < 2; ++nf)
      bfr[nf] = *(const bf16x8*)&Bs[wc * 32 + nf * 16 + l15][l4 * 8];
#pragma unroll
    for (int mf = 0; mf < 2; ++mf)
#pragma unroll
      for (int nf = 0; nf < 2; ++nf)
        acc[mf][nf] = __builtin_amdgcn_mfma_f32_16x16x32_bf16(
            af[mf], bfr[nf], acc[mf][nf], 0, 0, 0);
    __syncthreads();
  }

  // C/D layout (m89): col = lane&15, row = (lane>>4)*4 + reg; fused LeakyReLU
#pragma unroll
  for (int mf = 0; mf < 2; ++mf)
#pragma unroll
    for (int nf = 0; nf < 2; ++nf)
#pragma unroll
      for (int r = 0; r < 4; ++r) {
        const int row = bm + wr * 32 + mf * 16 + l4 * 4 + r;
        const int col = bn + wc * 32 + nf * 16 + l15;
        float hval = acc[mf][nf][r];
        out[(size_t)row * DD + col] = (hval >= 0.f) ? hval : 0.2f * hval;
      }
}

extern "C" void kernel_launch(void* const* d_in, const int* in_sizes, int n_in,
                              void* d_out, int out_size, void* d_ws, size_t ws_size,
                              hipStream_t stream) {
  const float* x = (const float*)d_in[0];
  const float* W = (const float*)d_in[1];
  const float* a = (const float*)d_in[2];
  const int* gov = (const int*)d_in[4];

  float* p = (float*)d_ws;                   // 32 KB
  float* q = p + NN;                         // 32 KB
  float* u = q + NN;                         // 1 KB
  float* v = u + DD;                         // 1 KB
  int* inv = (int*)(v + DD);                 // 32 KB
  unsigned short* y = (unsigned short*)(inv + NN);  // 4 MB bf16

  hipLaunchKernelGGL(prep, dim3(1), dim3(1024), 0, stream, W, a, gov, u, v, inv);
  hipLaunchKernelGGL(pq_kernel, dim3(NN / 4), dim3(256), 0, stream, x, u, v, p, q);
  hipLaunchKernelGGL(combine, dim3(NN / 4), dim3(256), 0, stream,
                     x, p, q, gov, inv, y);
  hipLaunchKernelGGL(gemm_out, dim3(NN / BM, DD / BN), dim3(256), 0, stream,
                     y, W, (float*)d_out);
}